// Round 8
// baseline (288.636 us; speedup 1.0000x reference)
//
#include <hip/hip_runtime.h>
#include <hip/hip_bf16.h>
#include <math.h>

// Problem constants (FusedRoutedMLP)
#define E    8
#define H    1024
#define I2   2816          // 2*I
#define II   1408          // I
#define T    2048
#define KTOP 2
#define NP   (T * KTOP)    // 4096 (token, expert-slot) pairs

// GEMM tiling
#define BM   128
#define BK   32
#define BNA  64
#define BN2  128
#define GX   40
#define GXT  8             // extra gemm1 bx slots for the w2 transpose

// prep kernel block ranges: [route | cvt_x | w1 transpose (2 tiles/block)]
#define CVT_BLKS   1024
#define W1_TILES   (16 * 44 * E)        // 5632
#define W1_BLKS    (W1_TILES / 2)       // 2816
#define PREP_BLKS  (1 + CVT_BLKS + W1_BLKS)

// w2 transpose inside gemm1 tail blocks
#define W2_TILES     2816               // 22 * 16 * E
#define W2_BLOCKS    (GXT * 22)         // 176
#define W2_PER_BLOCK (W2_TILES / W2_BLOCKS)   // 16

typedef __attribute__((ext_vector_type(8))) short  short8v;
typedef __attribute__((ext_vector_type(4))) float  f32x4;
typedef __attribute__((ext_vector_type(8))) unsigned short ushort8;

#define VMCNT4() asm volatile("s_waitcnt vmcnt(4)" ::: "memory")
#define VMCNT0() asm volatile("s_waitcnt vmcnt(0)" ::: "memory")
#define BAR()    __builtin_amdgcn_s_barrier()

__device__ __forceinline__ void gload16(void* lds, const void* g) {
    __builtin_amdgcn_global_load_lds((const __attribute__((address_space(1))) unsigned int*)g,
                                     (__attribute__((address_space(3))) unsigned int*)lds,
                                     16, 0, 0);
}

// ---------------------------------------------------------------------------
// 64x64 fp32->bf16 transpose tile, split into async issue + process phases.
// Source index swizzled (c16 ^= r&15), read applies same swizzle (rule #21).
// ---------------------------------------------------------------------------
__device__ __forceinline__ void tr_issue(const float* __restrict__ src, int N,
                                         int k0, int n0, float* tile, int tid)
{
    int lane = tid & 63;
    int wv   = tid >> 6;
#pragma unroll
    for (int i = 0; i < 4; ++i) {
        int q   = (wv * 4 + i) * 64 + lane;
        int r   = q >> 4;
        int c16 = q & 15;
        gload16(tile + q * 4, src + (size_t)(k0 + r) * N + n0 + ((c16 ^ (r & 15)) << 2));
    }
}

__device__ __forceinline__ void tr_process(const float* tile,
                                           __hip_bfloat16* __restrict__ dst,
                                           int K, int k0, int n0, int tid)
{
    int n  = tid >> 2;
    int ks = (tid & 3) * 16;
    alignas(16) __hip_bfloat16 t[16];
#pragma unroll
    for (int j = 0; j < 16; ++j) {
        int r = ks + j;
        t[j] = __float2bfloat16(tile[r * 64 + (((n >> 2) ^ (r & 15)) << 2) + (n & 3)]);
    }
    __hip_bfloat16* d = dst + (size_t)(n0 + n) * K + k0 + ks;
    *(ushort8*)(d)     = ((ushort8*)t)[0];
    *(ushort8*)(d + 8) = ((ushort8*)t)[1];
}

// ---------------------------------------------------------------------------
// prep: {route (ballot sort) | x->bf16 | w1 transpose, 2 tiles/block 2-deep}
// ---------------------------------------------------------------------------
union PrepShared {
    float tile[2][4096];                       // 2 x 16 KB
    struct { int cnt4[4][E]; int woff[4][E]; } rt;
};

__launch_bounds__(256)
__global__ void prep_kernel(const float* __restrict__ x, const float* __restrict__ w1,
                            const int* __restrict__ ids,
                            __hip_bfloat16* __restrict__ xb,
                            __hip_bfloat16* __restrict__ w1t,
                            int* __restrict__ tok, int* __restrict__ inv,
                            int* __restrict__ seg_off, int* __restrict__ tile_off)
{
    __shared__ __align__(16) PrepShared sh;
    int tid = threadIdx.x;
    int b = blockIdx.x;

    if (b == 0) {
        int lane = tid & 63;
        int w    = tid >> 6;
        unsigned long long ltm = (1ull << lane) - 1ull;

        int wc = 0;
#pragma unroll 1
        for (int it = 0; it < 16; ++it) {
            int p = it * 256 + w * 64 + lane;
            int e = ids[p];
#pragma unroll
            for (int ee = 0; ee < E; ++ee) {
                unsigned long long m = __ballot(e == ee);
                if (lane == ee) wc += (int)__popcll(m);
            }
        }
        if (lane < E) sh.rt.cnt4[w][lane] = wc;
        __syncthreads();
        if (tid == 0) {
            int base = 0, tiles = 0;
            for (int e = 0; e < E; ++e) {
                seg_off[e]  = base;
                tile_off[e] = tiles;
                int tot = 0;
                for (int ww = 0; ww < 4; ++ww) {
                    sh.rt.woff[ww][e] = base + tot;
                    tot += sh.rt.cnt4[ww][e];
                }
                base  += tot;
                tiles += (tot + BM - 1) / BM;
            }
            seg_off[E]  = base;
            tile_off[E] = tiles;
        }
        __syncthreads();
        int run = (lane < E) ? sh.rt.woff[w][lane] : 0;
#pragma unroll 1
        for (int it = 0; it < 16; ++it) {
            int p = it * 256 + w * 64 + lane;
            int e = ids[p];
            unsigned long long me = 0;
            int acnt = 0;
#pragma unroll
            for (int ee = 0; ee < E; ++ee) {
                unsigned long long m = __ballot(e == ee);
                if (e == ee) me = m;
                if (lane == ee) acnt = (int)__popcll(m);
            }
            int rank = (int)__popcll(me & ltm);
            int qb   = __shfl(run, e, 64);
            int q    = qb + rank;
            tok[q] = p >> 1;
            inv[p] = q;
            run += acnt;
        }
        return;
    }
    b -= 1;

    if (b < CVT_BLKS) {
        int i = (b * 256 + tid) * 8;
        float4 a = *(const float4*)(x + i);
        float4 c = *(const float4*)(x + i + 4);
        alignas(16) __hip_bfloat16 t[8];
        t[0] = __float2bfloat16(a.x); t[1] = __float2bfloat16(a.y);
        t[2] = __float2bfloat16(a.z); t[3] = __float2bfloat16(a.w);
        t[4] = __float2bfloat16(c.x); t[5] = __float2bfloat16(c.y);
        t[6] = __float2bfloat16(c.z); t[7] = __float2bfloat16(c.w);
        *(ushort8*)(xb + i) = *(ushort8*)t;
        return;
    }
    b -= CVT_BLKS;

    // ---- w1 transpose: 2 tiles per block, pipelined 2-deep ----
    {
        int t0 = b * 2, t1 = b * 2 + 1;
        int e0 = t0 / 704, r0 = t0 % 704;
        int e1 = t1 / 704, r1 = t1 % 704;
        const float*    s0 = w1  + (size_t)e0 * H * I2;
        const float*    s1 = w1  + (size_t)e1 * H * I2;
        __hip_bfloat16* d0 = w1t + (size_t)e0 * I2 * H;
        __hip_bfloat16* d1 = w1t + (size_t)e1 * I2 * H;
        int k00 = (r0 / 44) * 64, n00 = (r0 % 44) * 64;
        int k01 = (r1 / 44) * 64, n01 = (r1 % 44) * 64;
        tr_issue(s0, I2, k00, n00, sh.tile[0], tid);
        tr_issue(s1, I2, k01, n01, sh.tile[1], tid);
        VMCNT4();
        BAR();
        tr_process(sh.tile[0], d0, H, k00, n00, tid);
        VMCNT0();
        BAR();
        tr_process(sh.tile[1], d1, H, k01, n01, tid);
    }
}

// ---------------------------------------------------------------------------
// GEMM1 + SiLU, double-buffered LDS, counted vmcnt.
// Tail blocks (bx >= GX) transpose w2, pipelined 2-deep.
// ---------------------------------------------------------------------------
union Gemm1Shared {
    struct {
        __hip_bfloat16 As[2][BM * BK];     // 2 x 8KB
        __hip_bfloat16 Bg[2][BNA * BK];    // 2 x 4KB
        __hip_bfloat16 Bu[2][BNA * BK];    // 2 x 4KB
        int tokS[BM];
    } g;                                    // ~33 KB
    float tile[2][4096];                    // 32 KB (w2 tail)
};

__launch_bounds__(256, 2)
__global__ void gemm1_silu(const __hip_bfloat16* __restrict__ xb,
                           const __hip_bfloat16* __restrict__ w1t,
                           const float* __restrict__ w2,
                           __hip_bfloat16* __restrict__ w2t,
                           const int* __restrict__ tok,
                           const int* __restrict__ seg_off,
                           const int* __restrict__ tile_off,
                           __hip_bfloat16* __restrict__ act)
{
    __shared__ __align__(16) Gemm1Shared sh;
    int tid = threadIdx.x;
    int bx = blockIdx.x;

    if (bx >= GX) {
        // ---- w2 transpose tail: 16 tiles, 2-deep pipeline ----
        int wid = (bx - GX) * 22 + blockIdx.y;        // 0..175
        int tbase = wid * W2_PER_BLOCK;
        // tile t: e = t/352, r = t%352, k0=(r>>4)*64, n0=(r&15)*64
        {
            int t = tbase;
            int e = t / 352, r = t % 352;
            tr_issue(w2 + (size_t)e * II * H, H, (r >> 4) * 64, (r & 15) * 64,
                     sh.tile[0], tid);
        }
#pragma unroll 1
        for (int i = 0; i < W2_PER_BLOCK; ++i) {
            int cur = i & 1;
            if (i < W2_PER_BLOCK - 1) {
                int t = tbase + i + 1;
                int e = t / 352, r = t % 352;
                tr_issue(w2 + (size_t)e * II * H, H, (r >> 4) * 64, (r & 15) * 64,
                         sh.tile[cur ^ 1], tid);
                VMCNT4();
            } else {
                VMCNT0();
            }
            BAR();
            {
                int t = tbase + i;
                int e = t / 352, r = t % 352;
                tr_process(sh.tile[cur], w2t + (size_t)e * H * II, II,
                           (r >> 4) * 64, (r & 15) * 64, tid);
            }
            BAR();
        }
        return;
    }

    if (bx >= tile_off[E]) return;
    int e = 0;
#pragma unroll
    for (int i = 1; i < E; ++i) if (bx >= tile_off[i]) e = i;
    int row0 = seg_off[e] + (bx - tile_off[e]) * BM;
    int rend = seg_off[e + 1];
    int jb   = blockIdx.y * BNA;

    if (tid < BM) {
        int gr = row0 + tid;
        sh.g.tokS[tid] = tok[gr < NP ? gr : NP - 1];
    }
    __syncthreads();

    int arow = tid >> 2;
    int aoff = (tid & 3) * 16;
    const char* xB  = (const char*)xb;
    const char* w1B = (const char*)(w1t + (size_t)e * I2 * H);
    const char* srcA0 = xB + (size_t)sh.g.tokS[arow]      * 2048 + aoff;
    const char* srcA1 = xB + (size_t)sh.g.tokS[arow + 64] * 2048 + aoff;
    const char* srcG  = w1B + (size_t)(jb + arow)      * 2048 + aoff;
    const char* srcU  = w1B + (size_t)(II + jb + arow) * 2048 + aoff;

    int lane = tid & 63;
    int w  = tid >> 6;
    int wm = w >> 1, wn = w & 1;
    int fr = lane & 15;
    int kc = lane >> 4;

    f32x4 accg[4][2] = {};
    f32x4 accu[4][2] = {};

    // prologue: stage tile 0 into buffer 0
    gload16(&sh.g.As[0][tid * 8], srcA0);
    gload16(&sh.g.As[0][2048 + tid * 8], srcA1);
    gload16(&sh.g.Bg[0][tid * 8], srcG);
    gload16(&sh.g.Bu[0][tid * 8], srcU);
    srcA0 += 64; srcA1 += 64; srcG += 64; srcU += 64;

#pragma unroll 1
    for (int t = 0; t < H / BK; ++t) {
        int cur = t & 1;
        if (t < H / BK - 1) {
            gload16(&sh.g.As[cur ^ 1][tid * 8], srcA0);
            gload16(&sh.g.As[cur ^ 1][2048 + tid * 8], srcA1);
            gload16(&sh.g.Bg[cur ^ 1][tid * 8], srcG);
            gload16(&sh.g.Bu[cur ^ 1][tid * 8], srcU);
            srcA0 += 64; srcA1 += 64; srcG += 64; srcU += 64;
            VMCNT4();
        } else {
            VMCNT0();
        }
        BAR();

        const short8v* Asv = (const short8v*)sh.g.As[cur];
        const short8v* Bgv = (const short8v*)sh.g.Bg[cur];
        const short8v* Buv = (const short8v*)sh.g.Bu[cur];
        short8v a[4], g[2], u[2];
#pragma unroll
        for (int m = 0; m < 4; ++m)
            a[m] = Asv[(wm * 64 + m * 16 + fr) * 4 + kc];
#pragma unroll
        for (int n = 0; n < 2; ++n) {
            g[n] = Bgv[(wn * 32 + n * 16 + fr) * 4 + kc];
            u[n] = Buv[(wn * 32 + n * 16 + fr) * 4 + kc];
        }
#pragma unroll
        for (int m = 0; m < 4; ++m)
#pragma unroll
            for (int n = 0; n < 2; ++n) {
                accg[m][n] = __builtin_amdgcn_mfma_f32_16x16x32_bf16(a[m], g[n], accg[m][n], 0, 0, 0);
                accu[m][n] = __builtin_amdgcn_mfma_f32_16x16x32_bf16(a[m], u[n], accu[m][n], 0, 0, 0);
            }
        BAR();
    }

#pragma unroll
    for (int m = 0; m < 4; ++m)
#pragma unroll
        for (int n = 0; n < 2; ++n) {
            int col = jb + wn * 32 + n * 16 + fr;
#pragma unroll
            for (int j = 0; j < 4; ++j) {
                int gr = row0 + wm * 64 + m * 16 + kc * 4 + j;
                if (gr < rend) {
                    float gg = accg[m][n][j];
                    float s  = gg / (1.0f + __expf(-gg));
                    act[(size_t)gr * II + col] = __float2bfloat16(s * accu[m][n][j]);
                }
            }
        }
}

// ---------------------------------------------------------------------------
// GEMM2: y[q] = act[q] . w2[e], double-buffered LDS, counted vmcnt.
// ---------------------------------------------------------------------------
__launch_bounds__(256, 2)
__global__ void gemm2(const __hip_bfloat16* __restrict__ act,
                      const __hip_bfloat16* __restrict__ w2t,
                      const int* __restrict__ seg_off,
                      const int* __restrict__ tile_off,
                      float* __restrict__ y)
{
    __shared__ __align__(16) __hip_bfloat16 As[2][BM * BK];    // 2 x 8KB
    __shared__ __align__(16) __hip_bfloat16 Bs[2][BN2 * BK];   // 2 x 8KB

    int bx = blockIdx.x;
    if (bx >= tile_off[E]) return;
    int e = 0;
#pragma unroll
    for (int i = 1; i < E; ++i) if (bx >= tile_off[i]) e = i;
    int row0 = seg_off[e] + (bx - tile_off[e]) * BM;
    int rend = seg_off[e + 1];
    int nb   = blockIdx.y * BN2;

    int tid = threadIdx.x;
    int arow = tid >> 2;
    int aoff = (tid & 3) * 16;
    const char* actB = (const char*)act;
    const char* w2B  = (const char*)(w2t + (size_t)e * H * II);
    int r0c = row0 + arow;       r0c = r0c < NP ? r0c : NP - 1;
    int r1c = row0 + arow + 64;  r1c = r1c < NP ? r1c : NP - 1;
    const char* srcA0 = actB + (size_t)r0c * 2816 + aoff;
    const char* srcA1 = actB + (size_t)r1c * 2816 + aoff;
    const char* srcB0 = w2B + (size_t)(nb + arow)      * 2816 + aoff;
    const char* srcB1 = w2B + (size_t)(nb + arow + 64) * 2816 + aoff;

    int lane = tid & 63;
    int w  = tid >> 6;
    int wm = w >> 1, wn = w & 1;
    int fr = lane & 15;
    int kc = lane >> 4;

    f32x4 acc[4][4] = {};

    gload16(&As[0][tid * 8], srcA0);
    gload16(&As[0][2048 + tid * 8], srcA1);
    gload16(&Bs[0][tid * 8], srcB0);
    gload16(&Bs[0][2048 + tid * 8], srcB1);
    srcA0 += 64; srcA1 += 64; srcB0 += 64; srcB1 += 64;

#pragma unroll 1
    for (int t = 0; t < II / BK; ++t) {
        int cur = t & 1;
        if (t < II / BK - 1) {
            gload16(&As[cur ^ 1][tid * 8], srcA0);
            gload16(&As[cur ^ 1][2048 + tid * 8], srcA1);
            gload16(&Bs[cur ^ 1][tid * 8], srcB0);
            gload16(&Bs[cur ^ 1][2048 + tid * 8], srcB1);
            srcA0 += 64; srcA1 += 64; srcB0 += 64; srcB1 += 64;
            VMCNT4();
        } else {
            VMCNT0();
        }
        BAR();

        const short8v* Asv = (const short8v*)As[cur];
        const short8v* Bsv = (const short8v*)Bs[cur];
        short8v a[4], b[4];
#pragma unroll
        for (int m = 0; m < 4; ++m)
            a[m] = Asv[(wm * 64 + m * 16 + fr) * 4 + kc];
#pragma unroll
        for (int n = 0; n < 4; ++n)
            b[n] = Bsv[(wn * 64 + n * 16 + fr) * 4 + kc];
#pragma unroll
        for (int m = 0; m < 4; ++m)
#pragma unroll
            for (int n = 0; n < 4; ++n)
                acc[m][n] = __builtin_amdgcn_mfma_f32_16x16x32_bf16(a[m], b[n], acc[m][n], 0, 0, 0);
        BAR();
    }

#pragma unroll
    for (int m = 0; m < 4; ++m)
#pragma unroll
        for (int n = 0; n < 4; ++n) {
            int col = nb + wn * 64 + n * 16 + fr;
#pragma unroll
            for (int j = 0; j < 4; ++j) {
                int lr = wm * 64 + m * 16 + kc * 4 + j;
                int gr = row0 + lr;
                if (gr < rend)
                    y[(size_t)gr * H + col] = acc[m][n][j];
            }
        }
}

// ---------------------------------------------------------------------------
// gather: out[t] = rw[t,0] * y[inv[2t]] + rw[t,1] * y[inv[2t+1]]
// ---------------------------------------------------------------------------
__global__ void gather_out(const float* __restrict__ y, const int* __restrict__ inv,
                           const float* __restrict__ rw, float* __restrict__ out)
{
    int gid = blockIdx.x * 256 + threadIdx.x;
    int t = gid >> 8;
    int c = (gid & 255) * 4;
    int q0 = inv[2 * t], q1 = inv[2 * t + 1];
    float w0 = rw[2 * t], w1 = rw[2 * t + 1];
    float4 a = *(const float4*)(y + (size_t)q0 * H + c);
    float4 b = *(const float4*)(y + (size_t)q1 * H + c);
    float4 o;
    o.x = w0 * a.x + w1 * b.x;
    o.y = w0 * a.y + w1 * b.y;
    o.z = w0 * a.z + w1 * b.z;
    o.w = w0 * a.w + w1 * b.w;
    *(float4*)(out + (size_t)t * H + c) = o;
}

// ---------------------------------------------------------------------------
extern "C" void kernel_launch(void* const* d_in, const int* in_sizes, int n_in,
                              void* d_out, int out_size, void* d_ws, size_t ws_size,
                              hipStream_t stream)
{
    const float* x   = (const float*)d_in[0];
    const int*   ids = (const int*)d_in[1];
    const float* rw  = (const float*)d_in[2];
    const float* w1  = (const float*)d_in[3];
    const float* w2  = (const float*)d_in[4];
    float*       out = (float*)d_out;

    char* ws = (char*)d_ws;
    int*   tok  = (int*)ws;
    int*   inv  = (int*)(ws + 16384);
    int*   seg  = (int*)(ws + 32768);
    int*   tile = (int*)(ws + 32768 + 64);
    __hip_bfloat16* xb  = (__hip_bfloat16*)(ws + 65536);
    __hip_bfloat16* w1t = (__hip_bfloat16*)(ws + 4259840);
    __hip_bfloat16* w2t = (__hip_bfloat16*)(ws + 50397184);
    __hip_bfloat16* act = (__hip_bfloat16*)(ws + 73465856);
    float*          y   = (float*)(ws + 85000192);

    prep_kernel<<<PREP_BLKS, 256, 0, stream>>>(x, w1, ids, xb, w1t, tok, inv, seg, tile);

    gemm1_silu<<<dim3(GX + GXT, II / BNA), 256, 0, stream>>>(xb, w1t, w2, w2t,
                                                             tok, seg, tile, act);
    gemm2<<<dim3(GX, H / BN2), 256, 0, stream>>>(act, w2t, seg, tile, y);
    gather_out<<<(T * H) / (256 * 4), 256, 0, stream>>>(y, inv, rw, out);
}